// Round 5
// baseline (40.786 us; speedup 1.0000x reference)
//
#include <hip/hip_runtime.h>

// Problem constants (match reference).
constexpr int B = 32, T = 4096, C = 32;
constexpr int NK = 3;     // W_ORDER = N_BREAKPOINTS - 1
constexpr int BVEC = 8;   // R1 best config

typedef float f32x4 __attribute__((ext_vector_type(4)));

// DIAGNOSTIC ROUND: identical kernel to R1 (12.94us single launch), launched
// 5x back-to-back (idempotent). dur_us = F + k_cold + 4*k_hot separates fixed
// per-measurement overhead F from true marginal kernel time k_hot.
//   k_hot ~5.5us (HBM floor) -> ~35us total; k_hot ~2-3us (L3-resident) -> ~23us;
//   k_hot ~13us (kernel genuinely slow) -> ~65us.
__global__ __launch_bounds__(256) void saaf_kernel(
    const float* __restrict__ x,
    const float* __restrict__ v,
    const float* __restrict__ w,
    float* __restrict__ out)
{
    const int tid = blockIdx.x * blockDim.x + threadIdx.x;
    const int c4  = tid & 7;             // 8 groups of 4 channels
    const int t   = (tid >> 3) & (T - 1);
    const int bg  = tid >> 15;           // 0..B/BVEC-1
    const int c0  = c4 * 4;

    // Breakpoint constants, replicated in f32 exactly as the reference:
    const float step = (float)(4096.0 / 3.0);   // 1365.3333740234375f
    float klo[NK], khi[NK], dk[NK], hdk2[NK];
#pragma unroll
    for (int k = 0; k < NK; ++k) {
        klo[k]  = (float)k * step;
        khi[k]  = (float)(k + 1) * step;
        dk[k]   = khi[k] - klo[k];
        hdk2[k] = (0.5f * dk[k]) * dk[k];       // 0.5*dk*dk, reference order
    }

    // Coefficient loads (2.5 MB total -> L2/L3 resident, reused 32x across b).
    float v0[4], v1[4], w0[4], w1[4], w2[4];
#pragma unroll
    for (int i = 0; i < 4; ++i) {
        const int c = c0 + i;
        v0[i] = v[(c * 2 + 0) * T + t];
        v1[i] = v[(c * 2 + 1) * T + t];
        w0[i] = w[(c * 3 + 0) * T + t];
        w1[i] = w[(c * 3 + 1) * T + t];
        w2[i] = w[(c * 3 + 2) * T + t];
    }

#pragma unroll
    for (int bb = 0; bb < BVEC; ++bb) {
        const int b = bg * BVEC + bb;
        const size_t base = ((size_t)b * T + t) * C + c0;
        const f32x4 xv = *(const f32x4*)&x[base];
        float os[4];
#pragma unroll
        for (int i = 0; i < 4; ++i) {
            const float xx = xv[i];
            float acc = v0[i] + xx * v1[i];          // sigma1
#pragma unroll
            for (int k = 0; k < NK; ++k) {
                const float d1 = xx - klo[k];
                const float f1 = 0.5f * (d1 * d1);
                const float f2 = hdk2[k] + dk[k] * (xx - khi[k]);
                const bool inside = (xx > klo[k]) && (xx < khi[k]);
                const float basis = inside ? f1 : f2;
                const float wk = (k == 0) ? w0[i] : (k == 1) ? w1[i] : w2[i];
                acc += basis * wk;                   // sigma2 accumulate
            }
            os[i] = acc;
        }
        f32x4 ov;
        ov[0] = os[0]; ov[1] = os[1]; ov[2] = os[2]; ov[3] = os[3];
        *(f32x4*)&out[base] = ov;
    }
}

extern "C" void kernel_launch(void* const* d_in, const int* in_sizes, int n_in,
                              void* d_out, int out_size, void* d_ws, size_t ws_size,
                              hipStream_t stream) {
    const float* x = (const float*)d_in[0];
    const float* v = (const float*)d_in[1];
    const float* w = (const float*)d_in[2];
    float* out = (float*)d_out;

    const int threads = (T * (C / 4)) * (B / BVEC);  // 131072
    const int block = 256;
    const int grid = threads / block;                // 512

    // 5 idempotent launches: slope of dur_us vs launch count = true marginal
    // kernel time, separating fixed overhead from kernel cost.
    for (int rep = 0; rep < 5; ++rep) {
        saaf_kernel<<<grid, block, 0, stream>>>(x, v, w, out);
    }
}

// Round 6
// 11.254 us; speedup vs baseline: 3.6242x; 3.6242x over previous
//
#include <hip/hip_runtime.h>

// Problem constants (match reference).
constexpr int B = 32, T = 4096, C = 32;
constexpr int NK = 3;     // W_ORDER = N_BREAKPOINTS - 1
constexpr int BVEC = 4;   // batches per thread; 1024 blocks = 16 waves/CU
constexpr int PAD = 33;   // LDS row stride (floats): 33 == 1 mod 32 -> <=2-way bank aliasing

typedef float f32x4 __attribute__((ext_vector_type(4)));

// out[b,t,c] = v[c,0,t] + x*v[c,1,t] + sum_k basis_k(x) * w[c,k,t]
//
// R5 diagnostic: marginal kernel time 7.0us vs 5.4us HBM floor; fixed launch
// overhead ~6us. This version: block-cooperative LDS staging of coefficients
// (coalesced, once per block) decouples coefficient-load redundancy from
// occupancy — 16 waves/CU at BVEC=4 with NO per-thread scattered loads
// (R4 showed scattered-load redundancy tax beats occupancy gain).
//
// Block geometry: 256 threads cover 32 t-values x 8 c4-groups; BVEC batches
// per thread. Grid = 128 t-blocks x 8 batch-groups = 1024 blocks.
// LDS: v 64 segs + w 96 segs, 32 floats each, stride PAD -> 20.6 KB/block
// (4 blocks/CU = 82KB < 160KB).
__global__ __launch_bounds__(256) void saaf_kernel(
    const float* __restrict__ x,
    const float* __restrict__ v,
    const float* __restrict__ w,
    float* __restrict__ out)
{
    __shared__ float lv[64 * PAD];   // v[c][j][tl] at (c*2+j)*PAD + tl
    __shared__ float lw[96 * PAD];   // w[c][k][tl] at (c*3+k)*PAD + tl

    const int tid = threadIdx.x;
    const int bt  = blockIdx.x & 127;    // t-block
    const int bg  = blockIdx.x >> 7;     // batch group 0..7
    const int t0  = bt * 32;

    // ---- Cooperative coefficient staging (fully coalesced: 32 lanes read
    // 128B contiguous per segment; v is [C][2][T] so seg=c*2+j is linear) ----
#pragma unroll
    for (int i = 0; i < 8; ++i) {                 // 64 segs * 32 floats
        const int idx = i * 256 + tid;
        const int seg = idx >> 5, tl = idx & 31;
        lv[seg * PAD + tl] = v[seg * T + t0 + tl];
    }
#pragma unroll
    for (int i = 0; i < 12; ++i) {                // 96 segs * 32 floats
        const int idx = i * 256 + tid;
        const int seg = idx >> 5, tl = idx & 31;
        lw[seg * PAD + tl] = w[seg * T + t0 + tl];
    }
    __syncthreads();

    const int c4 = tid & 7;          // 8 groups of 4 channels
    const int tl = tid >> 3;         // 0..31 local t
    const int c0 = c4 * 4;
    const int t  = t0 + tl;

    // Breakpoint constants, f32 exactly as the reference:
    const float step = (float)(4096.0 / 3.0);   // 1365.3333740234375f
    float klo[NK], khi[NK], dk[NK], hdk2[NK];
#pragma unroll
    for (int k = 0; k < NK; ++k) {
        klo[k]  = (float)k * step;
        khi[k]  = (float)(k + 1) * step;
        dk[k]   = khi[k] - klo[k];
        hdk2[k] = (0.5f * dk[k]) * dk[k];       // 0.5*dk*dk, reference order
    }

    // Per-thread coefficients from LDS (<=2-way bank aliasing -> free).
    float v0[4], v1[4], w0[4], w1[4], w2[4];
#pragma unroll
    for (int i = 0; i < 4; ++i) {
        const int c = c0 + i;
        v0[i] = lv[(c * 2 + 0) * PAD + tl];
        v1[i] = lv[(c * 2 + 1) * PAD + tl];
        w0[i] = lw[(c * 3 + 0) * PAD + tl];
        w1[i] = lw[(c * 3 + 1) * PAD + tl];
        w2[i] = lw[(c * 3 + 2) * PAD + tl];
    }

    // Prefetch all BVEC x-vectors first (max MLP), then compute+store.
    f32x4 xv[BVEC];
#pragma unroll
    for (int bb = 0; bb < BVEC; ++bb) {
        const int b = bg * BVEC + bb;
        xv[bb] = *(const f32x4*)&x[((size_t)b * T + t) * C + c0];
    }

#pragma unroll
    for (int bb = 0; bb < BVEC; ++bb) {
        const int b = bg * BVEC + bb;
        float os[4];
#pragma unroll
        for (int i = 0; i < 4; ++i) {
            const float xx = xv[bb][i];
            float acc = v0[i] + xx * v1[i];          // sigma1
#pragma unroll
            for (int k = 0; k < NK; ++k) {
                const float d1 = xx - klo[k];
                const float f1 = 0.5f * (d1 * d1);
                const float f2 = hdk2[k] + dk[k] * (xx - khi[k]);
                const bool inside = (xx > klo[k]) && (xx < khi[k]);
                const float basis = inside ? f1 : f2;
                const float wk = (k == 0) ? w0[i] : (k == 1) ? w1[i] : w2[i];
                acc += basis * wk;                   // sigma2 accumulate
            }
            os[i] = acc;
        }
        f32x4 ov;
        ov[0] = os[0]; ov[1] = os[1]; ov[2] = os[2]; ov[3] = os[3];
        *(f32x4*)&out[((size_t)b * T + t) * C + c0] = ov;
    }
}

extern "C" void kernel_launch(void* const* d_in, const int* in_sizes, int n_in,
                              void* d_out, int out_size, void* d_ws, size_t ws_size,
                              hipStream_t stream) {
    const float* x = (const float*)d_in[0];
    const float* v = (const float*)d_in[1];
    const float* w = (const float*)d_in[2];
    float* out = (float*)d_out;

    // Grid: 128 t-blocks * (B/BVEC=8) batch groups = 1024 blocks of 256.
    const int grid = (T / 32) * (B / BVEC);
    saaf_kernel<<<grid, 256, 0, stream>>>(x, v, w, out);
}